// Round 10
// baseline (121.619 us; speedup 1.0000x reference)
//
#include <hip/hip_runtime.h>

// Problem constants: B=4, C=32, H=W=256, heads=4, head_dim=8, amp=2.
#define Bdim 4
#define Cdim 32
#define NH   4
#define HD   8
#define Hdim 256
#define Wdim 256
#define AMP  2
#define KS   5

// Per-block: ONE 64-lane wave, ONE head, 32 px x 8 rows. Barrier-free: the
// wave consumes only LDS it wrote itself (lgkmcnt dependency). Head-mean via
// device-scope atomicAdd on zero-inited out.
#define XT    32
#define TY    8
#define TROWS 12                    // TY + 2*AMP
#define TPOS  40                    // pos 0..39 staged; any 8/16-lane b128 phase
                                    // covers 32/64 consecutive words -> <=2-way (free)
#define NPAIRS 4                    // 4 d-pairs (one head)
#define PAIR_STRIDE (TROWS * TPOS)  // 480
#define TILE_SLOTS (NPAIRS * PAIR_STRIDE)   // 1920 floats = 7.5 KB

typedef _Float16 h2 __attribute__((ext_vector_type(2)));

static __device__ __forceinline__ float dot2acc(h2 a, h2 b, float c) {
#if __has_builtin(__builtin_amdgcn_fdot2)
    return __builtin_amdgcn_fdot2(a, b, c, false);
#else
    return c + (float)a.x * (float)b.x + (float)a.y * (float)b.y;
#endif
}

__global__ __launch_bounds__(256) void zero_out_kernel(float* __restrict__ out) {
    // 2*4*65536 floats = 131072 float4
    ((float4*)out)[blockIdx.x * 256 + threadIdx.x] = make_float4(0.f, 0.f, 0.f, 0.f);
}

// (64,4): VGPR cap 128 — round 8's identical body ran spill-free at this cap
// (round 6's disaster was cap=64).
__global__ __launch_bounds__(64, 4) void natt_head_kernel(
    const float* __restrict__ xq,
    const float* __restrict__ xk,
    float* __restrict__ out)        // (B, 2, H, W), pre-zeroed
{
    __shared__ __align__(16) float kt[TILE_SLOTS];

    const int lane = threadIdx.x;
    const int bid  = blockIdx.x;     // 0..4095
    // XCD swizzle: bid%8 = XCD; contiguous 32-row y-slab per XCD.
    const int xcd = bid & 7;
    const int u   = bid >> 3;
    const int yt  = xcd * 4 + (u & 3);   // 0..31
    const int v   = u >> 2;
    const int xt  = v & 7;               // 0..7
    const int w2  = v >> 3;
    const int h   = w2 & 3;              // head
    const int b   = w2 >> 2;             // batch

    const int Y0 = yt * TY;
    const int X0 = xt * XT;
    const bool interior = (yt != 0) && (yt != 31) && (xt != 0) && (xt != 7);

    const int row = lane >> 3;       // 0..7
    const int qx  = lane & 7;        // 0..7 (4 px)
    const int y   = Y0 + row;
    const int x0  = X0 + qx * 4;

    const size_t plane = (size_t)Hdim * Wdim;
    const float scale = 0.35355339059327373f;   // 8^-0.5

    // ---- stage this head's 4 d-pairs: 4 x 12 rows x 10 chunks = 480 float4
    // jobs (7.5/lane). Chunk c4 covers pos 4c4..4c4+3 <-> x = X0-6+4c4.
    {
        const float* kb = xk + (size_t)b * Cdim * plane;
        if (interior) {
            #pragma unroll
            for (int it = 0; it < 8; ++it) {
                const int j = lane + it * 64;
                if (j < NPAIRS * TROWS * 10) {
                    const int c4 = j % 10;
                    const int t  = j / 10;
                    const int rw = t % TROWS;
                    const int d2 = t / TROWS;            // d-pair 0..3
                    const int c0 = 8 * d2 + h;           // channel of d=2*d2
                    const int yr = Y0 - AMP + rw;        // 6..247: in range
                    const int xs = X0 - 6 + c4 * 4;      // 26..222: in range
                    const float* pa = kb + (size_t)c0 * plane + (size_t)yr * Wdim + xs;
                    const float4 va = *(const float4*)pa;
                    const float4 vb = *(const float4*)(pa + 4 * plane);
                    const float a[4]  = {va.x, va.y, va.z, va.w};
                    const float bb[4] = {vb.x, vb.y, vb.z, vb.w};
                    float o[4];
                    #pragma unroll
                    for (int k2 = 0; k2 < 4; ++k2) {
                        h2 pk;
                        pk.x = (_Float16)a[k2];
                        pk.y = (_Float16)bb[k2];
                        o[k2] = __builtin_bit_cast(float, pk);
                    }
                    *(float4*)(kt + d2 * PAIR_STRIDE + rw * TPOS + c4 * 4) =
                        make_float4(o[0], o[1], o[2], o[3]);
                }
            }
        } else {
            // clamped loads + register rotate: every VALID slot exact;
            // out-of-image slots hold finite garbage read only by masked taps.
            #pragma unroll
            for (int it = 0; it < 8; ++it) {
                const int j = lane + it * 64;
                if (j < NPAIRS * TROWS * 10) {
                    const int c4 = j % 10;
                    const int t  = j / 10;
                    const int rw = t % TROWS;
                    const int d2 = t / TROWS;
                    const int c0 = 8 * d2 + h;
                    int yr = Y0 - AMP + rw;
                    yr = yr < 0 ? 0 : (yr > Hdim - 1 ? Hdim - 1 : yr);
                    const int xs = X0 - 6 + c4 * 4;
                    const int xc = xs < 0 ? 0 : (xs > Wdim - 4 ? Wdim - 4 : xs);
                    const int sh = xs - xc;              // -6, -2, 0, +2
                    const float* pa = kb + (size_t)c0 * plane + (size_t)yr * Wdim + xc;
                    const float4 va = *(const float4*)pa;
                    const float4 vb = *(const float4*)(pa + 4 * plane);
                    const float a[4]  = {va.x, va.y, va.z, va.w};
                    const float bb[4] = {vb.x, vb.y, vb.z, vb.w};
                    float o[4];
                    #pragma unroll
                    for (int k2 = 0; k2 < 4; ++k2) {
                        int idx = k2 + sh;
                        idx = idx < 0 ? 0 : (idx > 3 ? 3 : idx);
                        h2 pk;
                        pk.x = (_Float16)a[idx];
                        pk.y = (_Float16)bb[idx];
                        o[k2] = __builtin_bit_cast(float, pk);
                    }
                    *(float4*)(kt + d2 * PAIR_STRIDE + rw * TPOS + c4 * 4) =
                        make_float4(o[0], o[1], o[2], o[3]);
                }
            }
        }
    }

    // ---- q fragments, packed f16x2 by d-pair, 4 px each
    const float* qb = xq + (size_t)b * Cdim * plane + (size_t)y * Wdim + x0;
    h2 q2[4][4];
    #pragma unroll
    for (int d2 = 0; d2 < 4; ++d2) {
        const float4 qa = *(const float4*)(qb + (size_t)((2 * d2)     * NH + h) * plane);
        const float4 qc = *(const float4*)(qb + (size_t)((2 * d2 + 1) * NH + h) * plane);
        const float qa4[4] = {qa.x, qa.y, qa.z, qa.w};
        const float qc4[4] = {qc.x, qc.y, qc.z, qc.w};
        #pragma unroll
        for (int p = 0; p < 4; ++p) {
            q2[d2][p].x = (_Float16)(qa4[p] * scale);
            q2[d2][p].y = (_Float16)(qc4[p] * scale);
        }
    }

    // No barrier: single-wave block, own-wave LDS dependency only.

    float Z[4]  = {0.f, 0.f, 0.f, 0.f};
    float sx[4] = {0.f, 0.f, 0.f, 0.f};
    float sy[4] = {0.f, 0.f, 0.f, 0.f};

    #pragma unroll
    for (int r = 0; r < KS; ++r) {
        float dot[KS][4];
        #pragma unroll
        for (int dj = 0; dj < KS; ++dj) {
            dot[dj][0] = 0.f; dot[dj][1] = 0.f; dot[dj][2] = 0.f; dot[dj][3] = 0.f;
        }

        #pragma unroll
        for (int d2 = 0; d2 < 4; ++d2) {
            // 8-pos window: pos qx*4+4 .. qx*4+11, two aligned b128s
            const float* wp = kt + d2 * PAIR_STRIDE + (row + r) * TPOS + (qx * 4 + 4);
            const float4 wa = *(const float4*)wp;
            const float4 wb = *(const float4*)(wp + 4);
            const float wf[8] = {wa.x, wa.y, wa.z, wa.w, wb.x, wb.y, wb.z, wb.w};
            h2 w[8];
            #pragma unroll
            for (int k2 = 0; k2 < 8; ++k2) w[k2] = __builtin_bit_cast(h2, wf[k2]);
            #pragma unroll
            for (int dj = 0; dj < KS; ++dj) {
                #pragma unroll
                for (int p = 0; p < 4; ++p)
                    dot[dj][p] = dot2acc(q2[d2][p], w[p + dj], dot[dj][p]);
            }
        }

        const float fdi = (float)(r - AMP);
        if (interior) {                        // block-uniform: no masks
            #pragma unroll
            for (int p = 0; p < 4; ++p) {
                float e[KS];
                #pragma unroll
                for (int dj = 0; dj < KS; ++dj) e[dj] = __expf(dot[dj][p]);
                const float er = ((e[0] + e[1]) + (e[2] + e[3])) + e[4];
                Z[p]  += er;
                sx[p] += fdi * er;
                sy[p] += (e[3] - e[1]) + 2.f * (e[4] - e[0]);
            }
        } else {
            const int yy = y + r - AMP;
            const bool rowok = (yy >= 0) && (yy < Hdim);
            #pragma unroll
            for (int p = 0; p < 4; ++p) {
                float e[KS];
                #pragma unroll
                for (int dj = 0; dj < KS; ++dj) {
                    const int xx = x0 + p + dj - AMP;
                    const bool ok = rowok && (xx >= 0) && (xx < Wdim);
                    e[dj] = ok ? __expf(dot[dj][p]) : 0.f;
                }
                const float er = ((e[0] + e[1]) + (e[2] + e[3])) + e[4];
                Z[p]  += er;
                sx[p] += fdi * er;
                sy[p] += (e[3] - e[1]) + 2.f * (e[4] - e[0]);
            }
        }
    }

    // ---- head contribution directly into out (pre-zeroed): out += 0.25*v_head.
    // Device-scope atomics; fp-add order noise ~1e-6 << threshold.
    float* o0 = out + (size_t)(b * 2) * plane + (size_t)y * Wdim + x0;
    #pragma unroll
    for (int p = 0; p < 4; ++p) {
        const float inv = 0.25f / Z[p];
        atomicAdd(o0 + p,         sx[p] * inv);
        atomicAdd(o0 + plane + p, sy[p] * inv);
    }
}

extern "C" void kernel_launch(void* const* d_in, const int* in_sizes, int n_in,
                              void* d_out, int out_size, void* d_ws, size_t ws_size,
                              hipStream_t stream) {
    const float* xq = (const float*)d_in[0];
    const float* xk = (const float*)d_in[1];
    float* out = (float*)d_out;

    zero_out_kernel<<<dim3(512, 1, 1), dim3(256, 1, 1), 0, stream>>>(out);
    // 32 y x 8 x x 4 heads x 4 batches = 4096 single-wave blocks
    natt_head_kernel<<<dim3(4096, 1, 1), dim3(64, 1, 1), 0, stream>>>(xq, xk, out);
}

// Round 11
// 100.205 us; speedup vs baseline: 1.2137x; 1.2137x over previous
//
#include <hip/hip_runtime.h>

// Problem constants: B=4, C=32, H=W=256, heads=4, head_dim=8, amp=2.
#define Bdim 4
#define Cdim 32
#define NH   4
#define HD   8
#define Hdim 256
#define Wdim 256
#define AMP  2
#define KS   5

// Tile: 32 px x 8 rows, ALL 4 heads per 256-thread block; wave h = head h and
// stages ONLY its own head's 4 channel-pairs (same-wave dependency -> no
// staging barrier). LDS f16x2 pairs.
// TPOS=40 (no pad): staging jobs are exactly linear (lane -> word 4j, perfect
// bank stripe) and compute reads are 16B-aligned 32-bank phases — R10 measured
// 1.31M conflicts at TPOS=40 vs 4.08M at TPOS=44. Also 30 KB -> 5 blocks/CU.
#define XT    32
#define TY    8
#define TROWS 12                    // TY + 2*AMP
#define TPOS  40
#define NPAIRS 16                   // 4 heads * 4 d-pairs
#define PAIR_STRIDE (TROWS * TPOS)  // 480
#define TILE_SLOTS (NPAIRS * PAIR_STRIDE)   // 7680 * 4B = 30 KB

typedef _Float16 h2 __attribute__((ext_vector_type(2)));

static __device__ __forceinline__ float dot2acc(h2 a, h2 b, float c) {
#if __has_builtin(__builtin_amdgcn_fdot2)
    return __builtin_amdgcn_fdot2(a, b, c, false);
#else
    return c + (float)a.x * (float)b.x + (float)a.y * (float)b.y;
#endif
}

__global__ __launch_bounds__(256) void natt_offset_kernel(
    const float* __restrict__ xq,
    const float* __restrict__ xk,
    float* __restrict__ out)
{
    __shared__ __align__(16) float kt[TILE_SLOTS];

    const int tid = threadIdx.x;
    // XCD swizzle: bid%8 = XCD; contiguous 32-row y-slab per XCD (FETCH ~35 MB).
    const int bid = blockIdx.x;
    const int r8  = bid & 7;
    const int u   = bid >> 3;
    const int yt  = r8 * 4 + (u & 3);   // 0..31
    const int rst = u >> 2;
    const int xt  = rst & 7;            // 0..7
    const int b   = rst >> 3;           // 0..3

    const int Y0 = yt * TY;
    const int X0 = xt * XT;
    const bool interior = (yt != 0) && (yt != 31) && (xt != 0) && (xt != 7);

    const int h    = tid >> 6;          // wave = head
    const int lane = tid & 63;
    const int row  = lane >> 3;         // 0..7
    const int qx   = lane & 7;          // 0..7 (4 px)
    const int y    = Y0 + row;
    const int x0   = X0 + qx * 4;

    const size_t plane = (size_t)Hdim * Wdim;
    const float scale = 0.35355339059327373f;   // 8^-0.5

    // ---- per-wave staging of this head's 4 d-pairs: 4 x 12 rows x 10 chunks
    // = 480 float4 jobs per wave. Chunk c4 covers pos 4c4..4c4+3 <-> x = X0-6+4c4.
    {
        const float* kb = xk + (size_t)b * Cdim * plane;
        if (interior) {
            // no y-clamp (6<=yr<=247), no x-clamp (26<=xs<=222): straight pack
            #pragma unroll
            for (int it = 0; it < 8; ++it) {
                const int j = lane + it * 64;
                if (j < 4 * TROWS * 10) {
                    const int c4 = j % 10;
                    const int t  = j / 10;
                    const int rw = t % TROWS;
                    const int d2 = t / TROWS;            // d-pair 0..3
                    const int c0 = 8 * d2 + h;           // channel of d=2*d2
                    const int yr = Y0 - AMP + rw;
                    const int xs = X0 - 6 + c4 * 4;
                    const float* pa = kb + (size_t)c0 * plane + (size_t)yr * Wdim + xs;
                    const float4 va = *(const float4*)pa;
                    const float4 vb = *(const float4*)(pa + 4 * plane);
                    const float a[4]  = {va.x, va.y, va.z, va.w};
                    const float bb[4] = {vb.x, vb.y, vb.z, vb.w};
                    float o[4];
                    #pragma unroll
                    for (int k2 = 0; k2 < 4; ++k2) {
                        h2 pk;
                        pk.x = (_Float16)a[k2];
                        pk.y = (_Float16)bb[k2];
                        o[k2] = __builtin_bit_cast(float, pk);
                    }
                    *(float4*)(kt + ((d2 << 2) | h) * PAIR_STRIDE + rw * TPOS + c4 * 4) =
                        make_float4(o[0], o[1], o[2], o[3]);
                }
            }
        } else {
            // clamped loads + register rotate: every VALID slot exact; out-of-image
            // slots hold finite garbage read only by masked taps.
            #pragma unroll
            for (int it = 0; it < 8; ++it) {
                const int j = lane + it * 64;
                if (j < 4 * TROWS * 10) {
                    const int c4 = j % 10;
                    const int t  = j / 10;
                    const int rw = t % TROWS;
                    const int d2 = t / TROWS;
                    const int c0 = 8 * d2 + h;
                    int yr = Y0 - AMP + rw;
                    yr = yr < 0 ? 0 : (yr > Hdim - 1 ? Hdim - 1 : yr);
                    const int xs = X0 - 6 + c4 * 4;
                    const int xc = xs < 0 ? 0 : (xs > Wdim - 4 ? Wdim - 4 : xs);
                    const int sh = xs - xc;              // -6, -2, 0, +2
                    const float* pa = kb + (size_t)c0 * plane + (size_t)yr * Wdim + xc;
                    const float4 va = *(const float4*)pa;
                    const float4 vb = *(const float4*)(pa + 4 * plane);
                    const float a[4]  = {va.x, va.y, va.z, va.w};
                    const float bb[4] = {vb.x, vb.y, vb.z, vb.w};
                    float o[4];
                    #pragma unroll
                    for (int k2 = 0; k2 < 4; ++k2) {
                        int idx = k2 + sh;
                        idx = idx < 0 ? 0 : (idx > 3 ? 3 : idx);
                        h2 pk;
                        pk.x = (_Float16)a[idx];
                        pk.y = (_Float16)bb[idx];
                        o[k2] = __builtin_bit_cast(float, pk);
                    }
                    *(float4*)(kt + ((d2 << 2) | h) * PAIR_STRIDE + rw * TPOS + c4 * 4) =
                        make_float4(o[0], o[1], o[2], o[3]);
                }
            }
        }
    }

    // ---- q fragments for this head, packed f16x2 by d-pair, 4 px each
    const float* qb = xq + (size_t)b * Cdim * plane + (size_t)y * Wdim + x0;
    h2 q2[4][4];
    #pragma unroll
    for (int d2 = 0; d2 < 4; ++d2) {
        const float4 qa = *(const float4*)(qb + (size_t)((2 * d2)     * NH + h) * plane);
        const float4 qc = *(const float4*)(qb + (size_t)((2 * d2 + 1) * NH + h) * plane);
        const float qa4[4] = {qa.x, qa.y, qa.z, qa.w};
        const float qc4[4] = {qc.x, qc.y, qc.z, qc.w};
        #pragma unroll
        for (int p = 0; p < 4; ++p) {
            q2[d2][p].x = (_Float16)(qa4[p] * scale);
            q2[d2][p].y = (_Float16)(qc4[p] * scale);
        }
    }

    // NO barrier here: this wave consumes only LDS it wrote itself; the
    // compiler's lgkmcnt on the ds_write->ds_read dependency is sufficient.

    float Z[4]  = {0.f, 0.f, 0.f, 0.f};
    float sx[4] = {0.f, 0.f, 0.f, 0.f};
    float sy[4] = {0.f, 0.f, 0.f, 0.f};

    #pragma unroll
    for (int r = 0; r < KS; ++r) {
        float dot[KS][4];
        #pragma unroll
        for (int dj = 0; dj < KS; ++dj) {
            dot[dj][0] = 0.f; dot[dj][1] = 0.f; dot[dj][2] = 0.f; dot[dj][3] = 0.f;
        }

        #pragma unroll
        for (int d2 = 0; d2 < 4; ++d2) {
            // 8-pos window: pos qx*4+4 .. qx*4+11, two aligned b128s
            const float* wp = kt + ((d2 << 2) | h) * PAIR_STRIDE
                                 + (row + r) * TPOS + (qx * 4 + 4);
            const float4 wa = *(const float4*)wp;
            const float4 wb = *(const float4*)(wp + 4);
            const float wf[8] = {wa.x, wa.y, wa.z, wa.w, wb.x, wb.y, wb.z, wb.w};
            h2 w[8];
            #pragma unroll
            for (int k2 = 0; k2 < 8; ++k2) w[k2] = __builtin_bit_cast(h2, wf[k2]);
            #pragma unroll
            for (int dj = 0; dj < KS; ++dj) {
                #pragma unroll
                for (int p = 0; p < 4; ++p)
                    dot[dj][p] = dot2acc(q2[d2][p], w[p + dj], dot[dj][p]);
            }
        }

        const float fdi = (float)(r - AMP);
        if (interior) {                        // block-uniform: no masks
            #pragma unroll
            for (int p = 0; p < 4; ++p) {
                float e[KS];
                #pragma unroll
                for (int dj = 0; dj < KS; ++dj) e[dj] = __expf(dot[dj][p]);
                const float er = ((e[0] + e[1]) + (e[2] + e[3])) + e[4];
                Z[p]  += er;
                sx[p] += fdi * er;
                sy[p] += (e[3] - e[1]) + 2.f * (e[4] - e[0]);
            }
        } else {
            const int yy = y + r - AMP;
            const bool rowok = (yy >= 0) && (yy < Hdim);
            #pragma unroll
            for (int p = 0; p < 4; ++p) {
                float e[KS];
                #pragma unroll
                for (int dj = 0; dj < KS; ++dj) {
                    const int xx = x0 + p + dj - AMP;
                    const bool ok = rowok && (xx >= 0) && (xx < Wdim);
                    e[dj] = ok ? __expf(dot[dj][p]) : 0.f;
                }
                const float er = ((e[0] + e[1]) + (e[2] + e[3])) + e[4];
                Z[p]  += er;
                sx[p] += fdi * er;
                sy[p] += (e[3] - e[1]) + 2.f * (e[4] - e[0]);
            }
        }
    }

    // ---- head mean through LDS (reuse kt; barrier before and after red writes).
    __syncthreads();
    float* red = kt;                     // 4 heads x 2 ch x 256 px = 2048 floats
    const int pxl = row * XT + qx * 4;
    {
        const float i0 = 1.f / Z[0], i1 = 1.f / Z[1], i2 = 1.f / Z[2], i3 = 1.f / Z[3];
        *(float4*)(red + (h * 2 + 0) * (XT * TY) + pxl) =
            make_float4(sx[0]*i0, sx[1]*i1, sx[2]*i2, sx[3]*i3);
        *(float4*)(red + (h * 2 + 1) * (XT * TY) + pxl) =
            make_float4(sy[0]*i0, sy[1]*i1, sy[2]*i2, sy[3]*i3);
    }
    __syncthreads();

    if (h < 2) {                         // ch 0 = row-offset (di), 1 = col-offset (dj)
        float acc[4] = {0.f, 0.f, 0.f, 0.f};
        #pragma unroll
        for (int hh = 0; hh < NH; ++hh) {
            const float4 v = *(const float4*)(red + (hh * 2 + h) * (XT * TY) + pxl);
            acc[0] += v.x; acc[1] += v.y; acc[2] += v.z; acc[3] += v.w;
        }
        *(float4*)(out + ((size_t)b * 2 + h) * plane + (size_t)y * Wdim + x0) =
            make_float4(acc[0]*0.25f, acc[1]*0.25f, acc[2]*0.25f, acc[3]*0.25f);
    }
}

extern "C" void kernel_launch(void* const* d_in, const int* in_sizes, int n_in,
                              void* d_out, int out_size, void* d_ws, size_t ws_size,
                              hipStream_t stream) {
    const float* xq = (const float*)d_in[0];
    const float* xk = (const float*)d_in[1];
    float* out = (float*)d_out;

    // 32 y-tiles x 8 x-tiles x 4 batches = 1024 blocks
    natt_offset_kernel<<<dim3(1024, 1, 1), dim3(256, 1, 1), 0, stream>>>(xq, xk, out);
}